// Round 1
// baseline (4540.574 us; speedup 1.0000x reference)
//
#include <hip/hip_runtime.h>
#include <hip/hip_bf16.h>

#define V 50257
#define L 4096
#define H1 30
#define H2 50
#define G1N 120   // 4*H1
#define G2N 200   // 4*H2

// ---- workspace layout (float offsets) ----
#define OFF_WIH1 16
#define OFF_WHH1 (OFF_WIH1 + G1N*H1)   // 3616
#define OFF_B1   (OFF_WHH1 + G1N*H1)   // 7216
#define OFF_WC   (OFF_B1 + G1N)        // 7336   Wc = w_ih2 @ w1  [200x30]
#define OFF_BC   (OFF_WC + G2N*H1)     // 13336  bc = w_ih2@bl1 + b_ih2 + b_hh2
#define OFF_WHH2 (OFF_BC + G2N)        // 13536
#define OFF_GX1  (OFF_WHH2 + G2N*H2)   // 23536  [4096 x 120]
#define OFF_H2   (OFF_GX1 + L*G1N)     // 515056 [4096 x 50]
// total ~720k floats = 2.88 MB of d_ws

__device__ __forceinline__ float fast_rcp(float x){
#if __has_builtin(__builtin_amdgcn_rcpf)
  return __builtin_amdgcn_rcpf(x);
#else
  return 1.f/x;
#endif
}
__device__ __forceinline__ float sigf(float x){
  return fast_rcp(1.f + __expf(-x));
}
__device__ __forceinline__ float tanh_f(float x){
  return 2.f*sigf(2.f*x) - 1.f;
}

template<int BF>
__device__ __forceinline__ float ldN(const void* p, long i){
  if (BF) return __bfloat162float(((const __hip_bfloat16*)p)[i]);
  return ((const float*)p)[i];
}
__device__ __forceinline__ float ldF(const void* p, long i, int bf){
  return bf ? __bfloat162float(((const __hip_bfloat16*)p)[i])
            : ((const float*)p)[i];
}

// ---- kernel 0: on-device dtype detection (fp32 vs bf16) ----
// bf16 data: every 16-bit half is a small bf16; bits[14:7] (exponent) land in
// ~[90,130] for N(0,0.05) values. fp32 data: those bits are low mantissa bits,
// ~uniform over [0,255] -> ~16% hit rate. 256-word vote separates cleanly.
__global__ void k_detect(const unsigned* emb, int* flag){
  __shared__ int cnt;
  if (threadIdx.x == 0) cnt = 0;
  __syncthreads();
  unsigned w = emb[threadIdx.x];
  unsigned e = (w >> 7) & 0xffu;   // bits [14:7] of the low 16-bit half
  int hit = (e >= 90u && e <= 130u) ? 1 : 0;
  atomicAdd(&cnt, hit);
  __syncthreads();
  if (threadIdx.x == 0) *flag = (cnt >= 192) ? 1 : 0;
}

// ---- kernel 1: convert small weights to fp32, fold Linear1 into LSTM2 input ----
__global__ void k_prep(float* ws, const void* w_ih1, const void* w_hh1,
                       const void* b_ih1, const void* b_hh1,
                       const void* w1, const void* bl1,
                       const void* w_ih2, const void* w_hh2,
                       const void* b_ih2, const void* b_hh2){
  int bf = ((const int*)ws)[0];
  int gid = blockIdx.x*blockDim.x + threadIdx.x;
  int gsz = gridDim.x*blockDim.x;
  for (int i=gid; i<G1N*H1; i+=gsz) ws[OFF_WIH1+i] = ldF(w_ih1,i,bf);
  for (int i=gid; i<G1N*H1; i+=gsz) ws[OFF_WHH1+i] = ldF(w_hh1,i,bf);
  for (int i=gid; i<G1N;    i+=gsz) ws[OFF_B1+i]   = ldF(b_ih1,i,bf)+ldF(b_hh1,i,bf);
  for (int i=gid; i<G2N*H2; i+=gsz) ws[OFF_WHH2+i] = ldF(w_hh2,i,bf);
  for (int i=gid; i<G2N; i+=gsz){
    float a = ldF(b_ih2,i,bf) + ldF(b_hh2,i,bf);
    for (int k=0;k<H2;k++) a += ldF(w_ih2,(long)i*H2+k,bf)*ldF(bl1,k,bf);
    ws[OFF_BC+i] = a;
  }
  for (int i=gid; i<G2N*H1; i+=gsz){
    int o = i / H1, j = i % H1;
    float a = 0.f;
    for (int k=0;k<H2;k++) a += ldF(w_ih2,(long)o*H2+k,bf)*ldF(w1,(long)k*H1+j,bf);
    ws[OFF_WC+i] = a;
  }
}

// ---- kernel 2: embedding gather + gx1 = emb[x] @ w_ih1^T + (b_ih1+b_hh1) ----
__global__ void k_embed(const int* __restrict__ x, const void* __restrict__ emb,
                        float* __restrict__ ws){
  int bf = ((const int*)ws)[0];
  __shared__ float er[2][H1];
  int half = threadIdx.x >> 7;       // 2 timesteps per block
  int lane = threadIdx.x & 127;
  int t = blockIdx.x*2 + half;
  int idx = x[t];
  if (lane < H1) er[half][lane] = ldF(emb,(long)idx*H1+lane,bf);
  __syncthreads();
  if (lane < G1N){
    const float* wi = ws + OFF_WIH1 + lane*H1;
    float a = ws[OFF_B1 + lane];
    #pragma unroll
    for (int k=0;k<H1;k++) a += er[half][k]*wi[k];
    ws[OFF_GX1 + (long)t*G1N + lane] = a;
  }
}

// ---- kernel 3: fused serial recurrence, lag-1 pipeline of LSTM1 & LSTM2 ----
// tid 0..119   : LSTM1 gates (step t),   weights w[0..29]
// tid 128..327 : LSTM2 gates (step t-1), w[0..29]=Wc row, w[32..81]=w_hh2 row
// tid 0..29    : c1/h1 update            tid 64..113 : c2/h2 update
__global__ __launch_bounds__(384) void k_recur(float* __restrict__ ws){
  const float* whh1 = ws + OFF_WHH1;
  const float* wcm  = ws + OFF_WC;
  const float* bcm  = ws + OFF_BC;
  const float* whh2 = ws + OFF_WHH2;
  const float* gx1  = ws + OFF_GX1;
  float* h2o = ws + OFF_H2;

  __shared__ __align__(16) float h1s[32];   // 30 + zero pad
  __shared__ __align__(16) float h2s[52];   // 50 + zero pad
  __shared__ float g1s[G1N];
  __shared__ float g2s[G2N];

  int tid = threadIdx.x;
  bool g1l = (tid < G1N);
  bool g2l = (tid >= 128) && (tid < 128 + G2N);
  int o2 = tid - 128;

  float w[84];
  #pragma unroll
  for (int k=0;k<84;k++) w[k] = 0.f;   // pads must be 0 (multiply vs. padded h)
  float bcv = 0.f;
  if (g1l){
    #pragma unroll
    for (int k=0;k<H1;k++) w[k] = whh1[tid*H1+k];
  } else if (g2l){
    #pragma unroll
    for (int k=0;k<H1;k++) w[k] = wcm[o2*H1+k];
    #pragma unroll
    for (int k=0;k<H2;k++) w[32+k] = whh2[o2*H2+k];
    bcv = bcm[o2];
  }
  bool u1l = (tid < H1);
  bool u2l = (tid >= 64) && (tid < 64 + H2);
  int j2 = tid - 64;
  float c1 = 0.f, c2 = 0.f;
  if (tid < 32) h1s[tid] = 0.f;
  if (tid < 52) h2s[tid] = 0.f;
  __syncthreads();

  float gv = g1l ? gx1[tid] : 0.f;   // prefetched gx1 row for step t
  for (int t=0; t<=L; ++t){
    // prefetch next gx1 row; latency hidden by a full iteration
    float gvn = (g1l && (t+1 < L)) ? gx1[(long)(t+1)*G1N + tid] : 0.f;

    if (g1l && t < L){
      float a0=gv, a1=0.f, a2=0.f, a3=0.f;
      const float4* hp = (const float4*)h1s;
      #pragma unroll
      for (int i=0;i<8;i++){
        float4 h4 = hp[i];
        a0 += w[4*i+0]*h4.x; a1 += w[4*i+1]*h4.y;
        a2 += w[4*i+2]*h4.z; a3 += w[4*i+3]*h4.w;
      }
      g1s[tid] = (a0+a1)+(a2+a3);
    }
    if (g2l && t >= 1){
      float a0=bcv, a1=0.f, a2=0.f, a3=0.f;
      const float4* hp = (const float4*)h1s;
      #pragma unroll
      for (int i=0;i<8;i++){
        float4 h4 = hp[i];
        a0 += w[4*i+0]*h4.x; a1 += w[4*i+1]*h4.y;
        a2 += w[4*i+2]*h4.z; a3 += w[4*i+3]*h4.w;
      }
      const float4* hq = (const float4*)h2s;
      #pragma unroll
      for (int i=0;i<13;i++){
        float4 h4 = hq[i];
        a0 += w[32+4*i+0]*h4.x; a1 += w[32+4*i+1]*h4.y;
        a2 += w[32+4*i+2]*h4.z; a3 += w[32+4*i+3]*h4.w;
      }
      g2s[o2] = (a0+a1)+(a2+a3);
    }
    __syncthreads();

    if (u1l && t < L){
      float gi=g1s[tid], gf=g1s[H1+tid], gg=g1s[2*H1+tid], go=g1s[3*H1+tid];
      c1 = sigf(gf)*c1 + sigf(gi)*tanh_f(gg);
      h1s[tid] = sigf(go)*tanh_f(c1);
    }
    if (u2l && t >= 1){
      float gi=g2s[j2], gf=g2s[H2+j2], gg=g2s[2*H2+j2], go=g2s[3*H2+j2];
      c2 = sigf(gf)*c2 + sigf(gi)*tanh_f(gg);
      float h = sigf(go)*tanh_f(c2);
      h2s[j2] = h;
      h2o[(long)(t-1)*H2 + j2] = h;   // fire-and-forget
    }
    __syncthreads();
    gv = gvn;
  }
}

// ---- kernel 4: out[r][c] = h2[r] . w2[c] + bl2[c]  (2 cols/thread) ----
template<int BF>
__device__ void gemm_body(const float* __restrict__ ws, const void* __restrict__ w2,
                          const void* __restrict__ bl2, void* __restrict__ outv){
  const float* __restrict__ h2 = ws + OFF_H2;
  int c  = blockIdx.x*512 + threadIdx.x*2;
  int r0 = blockIdx.y*128;
  long ca = (c   < V) ? c   : (V-1);
  long cb = (c+1 < V) ? c+1 : (V-1);
  float wa[H2], wb[H2];
  #pragma unroll
  for (int k=0;k<H2;k++){ wa[k]=ldN<BF>(w2, ca*H2+k); wb[k]=ldN<BF>(w2, cb*H2+k); }
  float bav = ldN<BF>(bl2, ca), bbv = ldN<BF>(bl2, cb);
  bool va = (c < V), vb = (c+1 < V);
  for (int r=r0; r<r0+128; ++r){
    const float* __restrict__ h = h2 + (long)r*H2;   // wave-uniform -> s_load
    float a0=bav, a1=0.f, b0=bbv, b1=0.f;
    #pragma unroll
    for (int k=0;k<H2;k+=2){
      float h0=h[k], h1v=h[k+1];
      a0 += h0*wa[k];   a1 += h1v*wa[k+1];
      b0 += h0*wb[k];   b1 += h1v*wb[k+1];
    }
    float ra = a0+a1, rb = b0+b1;
    long base = (long)r*V;
    if (BF){
      __hip_bfloat16* o = (__hip_bfloat16*)outv;
      if (va) o[base+c]   = __float2bfloat16(ra);
      if (vb) o[base+c+1] = __float2bfloat16(rb);
    } else {
      float* o = (float*)outv;
      if (va) o[base+c]   = ra;
      if (vb) o[base+c+1] = rb;
    }
  }
}

__global__ __launch_bounds__(256) void k_gemm(const float* __restrict__ ws,
                                              const void* __restrict__ w2,
                                              const void* __restrict__ bl2,
                                              void* __restrict__ outv){
  if (((const int*)ws)[0]) gemm_body<1>(ws, w2, bl2, outv);
  else                     gemm_body<0>(ws, w2, bl2, outv);
}

extern "C" void kernel_launch(void* const* d_in, const int* in_sizes, int n_in,
                              void* d_out, int out_size, void* d_ws, size_t ws_size,
                              hipStream_t stream){
  const int* x = (const int*)d_in[0];
  const void* emb = d_in[1];
  float* ws = (float*)d_ws;

  k_detect<<<1, 256, 0, stream>>>((const unsigned*)emb, (int*)d_ws);
  k_prep<<<64, 256, 0, stream>>>(ws, d_in[2], d_in[3], d_in[4], d_in[5],
                                 d_in[6], d_in[7], d_in[8], d_in[9],
                                 d_in[10], d_in[11]);
  k_embed<<<L/2, 256, 0, stream>>>(x, emb, ws);
  k_recur<<<1, 384, 0, stream>>>(ws);
  dim3 g((V + 511)/512, L/128);
  k_gemm<<<g, 256, 0, stream>>>(ws, d_in[12], d_in[13], d_out);
}